// Round 15
// baseline (37.940 us; speedup 1.0000x reference)
//
#include <hip/hip_runtime.h>
#include <hip/hip_bf16.h>

// OccupancyGridEMABatched:
//   out[v] = touched(v) ? max(0.95*grid[v], max_{pts at v} occ_val) : grid[v]
//
// R14 post-mortem: K1 ~29us vs ~14us floor. Root cause: 256 blocks on
// 256 CUs = 1 block/CU -- K1's barrier-separated phases (load->hist->scan->
// multisplit->flush) have no co-resident block to overlap with (R10's 12us
// K1 had 5 blocks/CU). R15:
//   * chunk=8192, 512 thr, ~41KB LDS -> 3 blocks/CU, phases overlap
//   * per-bucket regions padded to 4-record (16B) alignment; pads filled
//     with 0xFFFFFFFF = atomicMax no-op (int -1; idx bits hit voxel 16383
//     harmlessly) -> K2 gather is unconditional uint4 atomics, no masking
//   * K2 unchanged; 64B slices are L2/L3-resident (just written by K1)
// Packed 4B records: (val & 0xFFFFC000) | idx_low14 (18 value bits,
// err ~2^-8 << 2e-2 threshold). Deterministic: per-voxel max is
// order-insensitive to record order.

#define GRID_R          128
#define EMA_DEC         0.95f
#define NBUCKET         512           // 4 batches * 128 gx-planes
#define VOX_PER_BUCKET  16384         // 128*128 voxels = 64KB LDS
#define PTS_PER_BLOCK   8192
#define K1_THREADS      512
#define PTS_PER_THREAD  16            // 8192 / 512
#define REC_CAP         (PTS_PER_BLOCK + NBUCKET * 3)   // 9728 padded records

__device__ __forceinline__ int quant_clamp(float p) {
    // ((p/2 + 0.5) * 128) truncated; *0.5 and *128 are exact pow2 scalings
    // (FMA contraction cannot change the result since p*0.5f is exact).
    int g = (int)((p * 0.5f + 0.5f) * (float)GRID_R);
    return min(max(g, 0), GRID_R - 1);
}

// ------------------------------------------------------------------ K1
// Block-local multisplit with LDS staging and 4-record bucket padding:
// 8192 pts -> bucket-grouped, 16B-aligned-per-bucket chunk segment +
// transposed u16 offset table (padded offsets).
__global__ __launch_bounds__(512)
void occ_localsort5_kernel(const float* __restrict__ pts,
                           const float* __restrict__ occ_val,
                           const int*   __restrict__ bidx,
                           unsigned*        __restrict__ sorted,  // [nchunk*REC_CAP]
                           unsigned short*  __restrict__ offT,    // [513][nchunk]
                           int n_total, int nchunk) {
    extern __shared__ unsigned rec[];    // REC_CAP u32, dynamic (~38 KB)
    __shared__ int cur[NBUCKET];         // hist -> padded prefix -> cursor
    __shared__ int wsum[8];              // 8 scan waves (512 thr)
    __shared__ int sh_total;             // padded record total

    const int tid  = threadIdx.x;
    const int lane = tid & 63;
    const int wv   = tid >> 6;           // wave id 0..7
    const int c    = blockIdx.x;         // chunk id

    for (int b = tid; b < NBUCKET; b += K1_THREADS) cur[b] = 0;
    for (int j = tid; j < REC_CAP; j += K1_THREADS) rec[j] = 0xFFFFFFFFu;
    __syncthreads();

    const float4* pts4 = reinterpret_cast<const float4*>(pts);
    const float4* ov4  = reinterpret_cast<const float4*>(occ_val);
    const int4*   bi4  = reinterpret_cast<const int4*>(bidx);

    // statically-indexed -> stays in VGPRs (rule #20)
    int pk[PTS_PER_THREAD];
    int bk[PTS_PER_THREAD];

    #pragma unroll
    for (int r = 0; r < PTS_PER_THREAD / 8; ++r) {
        // 8-point group id; block owns groups [c*1024, c*1024+1024)
        const int i = c * ((PTS_PER_THREAD / 8) * K1_THREADS)
                    + r * K1_THREADS + tid;
        if (i * 8 + 7 < n_total) {
            float4 q0 = pts4[i * 6 + 0];
            float4 q1 = pts4[i * 6 + 1];
            float4 q2 = pts4[i * 6 + 2];
            float4 q3 = pts4[i * 6 + 3];
            float4 q4 = pts4[i * 6 + 4];
            float4 q5 = pts4[i * 6 + 5];
            float4 oa = ov4[i * 2 + 0];
            float4 ob = ov4[i * 2 + 1];
            int4   ba = bi4[i * 2 + 0];
            int4   bb = bi4[i * 2 + 1];

            float xs[8] = {q0.x, q0.w, q1.z, q2.y, q3.x, q3.w, q4.z, q5.y};
            float ys[8] = {q0.y, q1.x, q1.w, q2.z, q3.y, q4.x, q4.w, q5.z};
            float zs[8] = {q0.z, q1.y, q2.x, q2.w, q3.z, q4.y, q5.x, q5.w};
            int   vb[8] = {__float_as_int(oa.x), __float_as_int(oa.y),
                           __float_as_int(oa.z), __float_as_int(oa.w),
                           __float_as_int(ob.x), __float_as_int(ob.y),
                           __float_as_int(ob.z), __float_as_int(ob.w)};
            int   bs[8] = {ba.x, ba.y, ba.z, ba.w, bb.x, bb.y, bb.z, bb.w};

            #pragma unroll
            for (int k = 0; k < 8; ++k) {
                int gx = quant_clamp(xs[k]);
                int gy = quant_clamp(ys[k]);
                int gz = quant_clamp(zs[k]);
                int idx = bs[k] * (GRID_R * GRID_R * GRID_R)
                        + gx * (GRID_R * GRID_R) + gy * GRID_R + gz;
                pk[r * 8 + k] = (vb[k] & (int)0xFFFFC000) | (idx & 0x3FFF);
                bk[r * 8 + k] = idx >> 14;
            }
        } else {
            #pragma unroll
            for (int k = 0; k < 8; ++k) {
                bk[r * 8 + k] = -1;
                pk[r * 8 + k] = 0;
                int p = i * 8 + k;
                if (p < n_total) {
                    int gx = quant_clamp(pts[p * 3 + 0]);
                    int gy = quant_clamp(pts[p * 3 + 1]);
                    int gz = quant_clamp(pts[p * 3 + 2]);
                    int idx = bidx[p] * (GRID_R * GRID_R * GRID_R)
                            + gx * (GRID_R * GRID_R) + gy * GRID_R + gz;
                    pk[r * 8 + k] = (__float_as_int(occ_val[p]) & (int)0xFFFFC000)
                                  | (idx & 0x3FFF);
                    bk[r * 8 + k] = idx >> 14;
                }
            }
        }
    }

    // block-local histogram
    #pragma unroll
    for (int k = 0; k < PTS_PER_THREAD; ++k)
        if (bk[k] >= 0) atomicAdd(&cur[bk[k]], 1);
    __syncthreads();

    // scan of 4-ROUNDED counts: all 512 threads own bucket tid
    const int a  = cur[tid];
    const int ra = (a + 3) & ~3;          // padded count (16B granularity)
    int x = ra;
    #pragma unroll
    for (int off = 1; off < 64; off <<= 1) {
        int v = __shfl_up(x, off, 64);
        if (lane >= off) x += v;
    }
    if (lane == 63) wsum[wv] = x;
    __syncthreads();

    {
        int wofs = 0;
        #pragma unroll
        for (int w = 0; w < 8; ++w) if (w < wv) wofs += wsum[w];
        const int excl = x + wofs - ra;   // padded exclusive prefix
        offT[(size_t)tid * nchunk + c] = (unsigned short)excl;
        cur[tid] = excl;                  // cursor: records fill [excl, excl+a)
        if (tid == K1_THREADS - 1) {
            sh_total = excl + ra;         // padded grand total
            offT[(size_t)NBUCKET * nchunk + c] = (unsigned short)(excl + ra);
        }
    }
    __syncthreads();

    // multisplit into LDS (pads between buckets keep sentinel 0xFFFFFFFF)
    #pragma unroll
    for (int k = 0; k < PTS_PER_THREAD; ++k) {
        if (bk[k] >= 0) {
            int slot = atomicAdd(&cur[bk[k]], 1);
            rec[slot] = (unsigned)pk[k];
        }
    }
    __syncthreads();

    // dense coalesced flush (records + in-place sentinel pads)
    const int total = sh_total;
    unsigned* dst = sorted + (size_t)c * REC_CAP;
    for (int j = tid; j < total; j += K1_THREADS)
        dst[j] = rec[j];
}

// ------------------------------------------------------------------ K2
// One block per bucket, 1024 threads: 4 threads per chunk-slice on
// interleaved uint4 strides -- NO masking (slices 4-record aligned,
// pad words are atomicMax no-ops); LDS max; fused finalize.
__global__ __launch_bounds__(1024)
void occ_bucket8_kernel(const unsigned*       __restrict__ sorted,
                        const unsigned short* __restrict__ offT,
                        const float*          __restrict__ grid,
                        float*                __restrict__ out,
                        int nchunk) {
    __shared__ int smax[VOX_PER_BUCKET];    // 64 KB
    const int tid = threadIdx.x;
    // XCD-chunked bucket assignment: adjacent logical buckets land on the
    // same XCD -> shared L2 lines (512 = 8*64, bijective).
    const int b = (blockIdx.x & 7) * (NBUCKET / 8) + (blockIdx.x >> 3);

    int4* s4 = reinterpret_cast<int4*>(smax);
    for (int j = tid; j < VOX_PER_BUCKET / 4; j += 1024)
        s4[j] = make_int4(-1, -1, -1, -1);
    __syncthreads();

    const unsigned short* rowLo = offT + (size_t)b       * nchunk;
    const unsigned short* rowHi = offT + (size_t)(b + 1) * nchunk;

    // 4 threads per chunk: thread (c, p) reads uint4s at lo+4p, +16, ...
    // lo, hi both multiples of 4 -> every uint4 fully in-slice (real
    // records or sentinel pads, which are no-ops).
    for (int t = tid; t < nchunk * 4; t += 1024) {
        const int c  = t >> 2;
        const int p  = t & 3;
        const int lo = rowLo[c];
        const int hi = rowHi[c];
        const unsigned* rp = sorted + (size_t)c * REC_CAP;
        for (int j = lo + 4 * p; j < hi; j += 16) {
            uint4 e = *reinterpret_cast<const uint4*>(rp + j);
            atomicMax(&smax[e.x & (VOX_PER_BUCKET - 1)], (int)e.x);
            atomicMax(&smax[e.y & (VOX_PER_BUCKET - 1)], (int)e.y);
            atomicMax(&smax[e.z & (VOX_PER_BUCKET - 1)], (int)e.z);
            atomicMax(&smax[e.w & (VOX_PER_BUCKET - 1)], (int)e.w);
        }
    }
    __syncthreads();

    // fused finalize: each voxel of this bucket written exactly once.
    // packed sign bit = occ sign = 0 -> packed >= 0 -> sentinel -1 unambiguous.
    const size_t vbase = (size_t)b * VOX_PER_BUCKET;
    const float4* g4  = reinterpret_cast<const float4*>(grid + vbase);
    float4*       o4  = reinterpret_cast<float4*>(out + vbase);
    const int4*   sm4 = reinterpret_cast<const int4*>(smax);
    for (int j = tid; j < VOX_PER_BUCKET / 4; j += 1024) {
        int4   w = sm4[j];
        float4 g = g4[j];
        float4 r;
        r.x = (w.x == -1) ? g.x
            : fmaxf(EMA_DEC * g.x, __int_as_float(w.x & (int)0xFFFFC000));
        r.y = (w.y == -1) ? g.y
            : fmaxf(EMA_DEC * g.y, __int_as_float(w.y & (int)0xFFFFC000));
        r.z = (w.z == -1) ? g.z
            : fmaxf(EMA_DEC * g.z, __int_as_float(w.z & (int)0xFFFFC000));
        r.w = (w.w == -1) ? g.w
            : fmaxf(EMA_DEC * g.w, __int_as_float(w.w & (int)0xFFFFC000));
        o4[j] = r;
    }
}

// ------------------------------------------------- Fallback (proven R4 path)
__global__ void occ_scatter8_kernel(const float* __restrict__ pts,
                                    const float* __restrict__ occ_val,
                                    const int*   __restrict__ bidx,
                                    int*         __restrict__ out_bits,
                                    int n8, int n_total) {
    const int tid    = blockIdx.x * blockDim.x + threadIdx.x;
    const int stride = gridDim.x * blockDim.x;

    const float4* pts4 = reinterpret_cast<const float4*>(pts);
    const float4* ov4  = reinterpret_cast<const float4*>(occ_val);
    const int4*   bi4  = reinterpret_cast<const int4*>(bidx);

    for (int i = tid; i < n8; i += stride) {
        float4 q0 = pts4[i * 6 + 0];
        float4 q1 = pts4[i * 6 + 1];
        float4 q2 = pts4[i * 6 + 2];
        float4 q3 = pts4[i * 6 + 3];
        float4 q4 = pts4[i * 6 + 4];
        float4 q5 = pts4[i * 6 + 5];
        float4 oa = ov4[i * 2 + 0];
        float4 ob = ov4[i * 2 + 1];
        int4   ba = bi4[i * 2 + 0];
        int4   bb = bi4[i * 2 + 1];

        float xs[8] = {q0.x, q0.w, q1.z, q2.y, q3.x, q3.w, q4.z, q5.y};
        float ys[8] = {q0.y, q1.x, q1.w, q2.z, q3.y, q4.x, q4.w, q5.z};
        float zs[8] = {q0.z, q1.y, q2.x, q2.w, q3.z, q4.y, q5.x, q5.w};
        int   vb[8] = {__float_as_int(oa.x), __float_as_int(oa.y),
                       __float_as_int(oa.z), __float_as_int(oa.w),
                       __float_as_int(ob.x), __float_as_int(ob.y),
                       __float_as_int(ob.z), __float_as_int(ob.w)};
        int   bs[8] = {ba.x, ba.y, ba.z, ba.w, bb.x, bb.y, bb.z, bb.w};

        int idx[8];
        #pragma unroll
        for (int k = 0; k < 8; ++k) {
            int gx = quant_clamp(xs[k]);
            int gy = quant_clamp(ys[k]);
            int gz = quant_clamp(zs[k]);
            idx[k] = bs[k] * (GRID_R * GRID_R * GRID_R)
                   + gx * (GRID_R * GRID_R) + gy * GRID_R + gz;
        }
        #pragma unroll
        for (int k = 0; k < 8; ++k) atomicMax(&out_bits[idx[k]], vb[k]);
    }

    for (int i = n8 * 8 + tid; i < n_total; i += stride) {
        int gx = quant_clamp(pts[i * 3 + 0]);
        int gy = quant_clamp(pts[i * 3 + 1]);
        int gz = quant_clamp(pts[i * 3 + 2]);
        int idx = bidx[i] * (GRID_R * GRID_R * GRID_R)
                + gx * (GRID_R * GRID_R) + gy * GRID_R + gz;
        atomicMax(&out_bits[idx], __float_as_int(occ_val[i]));
    }
}

__global__ void occ_finalize_kernel(const float* __restrict__ grid,
                                    float*       __restrict__ out,
                                    int v4, int v_total) {
    const int tid    = blockIdx.x * blockDim.x + threadIdx.x;
    const int stride = gridDim.x * blockDim.x;

    const float4* g4 = reinterpret_cast<const float4*>(grid);
    int4*         w4 = reinterpret_cast<int4*>(out);
    float4*       o4 = reinterpret_cast<float4*>(out);

    for (int i = tid; i < v4; i += stride) {
        int4   w = w4[i];
        float4 g = g4[i];
        float4 r;
        r.x = (w.x == -1) ? g.x : fmaxf(EMA_DEC * g.x, __int_as_float(w.x));
        r.y = (w.y == -1) ? g.y : fmaxf(EMA_DEC * g.y, __int_as_float(w.y));
        r.z = (w.z == -1) ? g.z : fmaxf(EMA_DEC * g.z, __int_as_float(w.z));
        r.w = (w.w == -1) ? g.w : fmaxf(EMA_DEC * g.w, __int_as_float(w.w));
        o4[i] = r;
    }
    for (int i = v4 * 4 + tid; i < v_total; i += stride) {
        int w = reinterpret_cast<int*>(out)[i];
        float g = grid[i];
        out[i] = (w == -1) ? g : fmaxf(EMA_DEC * g, __int_as_float(w));
    }
}

// ---------------------------------------------------------------- launch
extern "C" void kernel_launch(void* const* d_in, const int* in_sizes, int n_in,
                              void* d_out, int out_size, void* d_ws, size_t ws_size,
                              hipStream_t stream) {
    const float* grid    = (const float*)d_in[0];   // (B,R,R,R) f32
    const float* pts     = (const float*)d_in[1];   // (N,3) f32
    const float* occ_val = (const float*)d_in[2];   // (N,) f32
    const int*   bidx    = (const int*)d_in[3];     // (N,) i32

    float* out = (float*)d_out;
    const int N = in_sizes[2];

    const int nchunk = (N + PTS_PER_BLOCK - 1) / PTS_PER_BLOCK;

    // ws layout: sorted[nchunk*REC_CAP] u32 | offT[513][nchunk] u16
    const size_t sorted_b = (size_t)nchunk * REC_CAP * sizeof(unsigned);
    const size_t off_b    = (size_t)(NBUCKET + 1) * nchunk * sizeof(unsigned short);
    const size_t need     = sorted_b + off_b + 16;
    const bool shape_ok   = (out_size == 4 * GRID_R * GRID_R * GRID_R);

    if (ws_size >= need && shape_ok && nchunk >= 1 && nchunk < 65536) {
        unsigned*       sorted = (unsigned*)d_ws;
        unsigned short* offT   = (unsigned short*)((char*)d_ws + sorted_b);

        occ_localsort5_kernel<<<nchunk, K1_THREADS,
                                REC_CAP * sizeof(unsigned), stream>>>(
            pts, occ_val, bidx, sorted, offT, N, nchunk);
        occ_bucket8_kernel<<<NBUCKET, 1024, 0, stream>>>(
            sorted, offT, grid, out, nchunk);
    } else {
        // fallback: sentinel memset + global atomic scatter + finalize
        hipMemsetAsync(d_out, 0xFF, (size_t)out_size * sizeof(float), stream);

        const int n8 = N / 8;
        int sblocks = (n8 + 255) / 256;
        if (sblocks < 1) sblocks = 1;
        occ_scatter8_kernel<<<sblocks, 256, 0, stream>>>(
            pts, occ_val, bidx, (int*)d_out, n8, N);

        const int v4 = out_size / 4;
        int fblocks = (v4 + 255) / 256;
        if (fblocks > 2048) fblocks = 2048;
        if (fblocks < 1) fblocks = 1;
        occ_finalize_kernel<<<fblocks, 256, 0, stream>>>(grid, out, v4, out_size);
    }
}